// Round 7
// baseline (353.647 us; speedup 1.0000x reference)
//
#include <hip/hip_runtime.h>
#include <hip/hip_bf16.h>
#include <stdint.h>

#define N_NODES 100000
#define N_EDGES 1280000
#define IN_DIM  256
#define OUT_DIM 64
#define NB1     98          // ceil(100000/1024) scan blocks
#define GB2     ((N_NODES + 127) / 128)   // 782 gemm blocks (128-row tiles)
#define PART_SZ 12500       // nodes per XCD partition (100000/8)

typedef __attribute__((ext_vector_type(8))) short bf16x8;
typedef __attribute__((ext_vector_type(4))) float f32x4;

__device__ __forceinline__ unsigned short f32_to_bf16(float f) {
    union { float f; unsigned int u; } c; c.f = f;
    unsigned int u = c.u;
    u += 0x7fffu + ((u >> 16) & 1u);   // RNE
    return (unsigned short)(u >> 16);
}
__device__ __forceinline__ float bf16_to_f32(unsigned short h) {
    union { unsigned int u; float f; } c; c.u = ((unsigned int)h) << 16; return c.f;
}

// ---------------------------------------------------------------------------
// K0: one-time W pack (f32 -> bf16, B-fragment order) + deg zeroing.
// ---------------------------------------------------------------------------
__global__ __launch_bounds__(256) void wpack_zero_kernel(const float* __restrict__ w,
                                                         unsigned short* __restrict__ wbf,
                                                         int* __restrict__ deg) {
    const int tid = threadIdx.x;
    const int base = blockIdx.x * 1024 + tid * 4;
    #pragma unroll
    for (int q = 0; q < 4; ++q) {
        const int i = base + q;
        if (i < N_NODES) deg[i] = 0;
    }
    if (blockIdx.x == 0) {
        for (int i = tid; i < IN_DIM * OUT_DIM; i += 256) {
            const int k = i >> 6, n = i & 63;
            const int kt = k >> 5, q = (k >> 3) & 3, j = k & 7;
            const int t = n >> 4, l = n & 15;
            wbf[((kt * 4 + t) * 64 + q * 16 + l) * 8 + j] = f32_to_bf16(w[i]);
        }
    }
}

// ---------------------------------------------------------------------------
// K1: GEMM (pre[N][64] bf16 = bf16(X)@bf16(W), MFMA 16x16x32) + hist tail.
// Round-14: REGISTER-MLP ARC CLOSED. Five attempts to keep 16 X-loads live in
// VGPRs (hoist / sched_barrier / WAR pipeline / inline asm / asm+waitcnt) all
// ended at VGPR_Count~48-64: on gfx950's unified file the RA spills the
// payload to AGPRs, and the accvgpr_write after each load re-serializes the
// chain. The un-defeatable latency hider is TLP guaranteed by block shape:
// 512-thread blocks (8 waves, ALWAYS co-resident) on a 128-row tile, same
// 32 KB LDS, same per-wave code with plain per-kt loads. One resident block
// = 8 waves/CU minimum; LDS(5)/threads(4) allow 4 blocks = 32 waves = 100%.
// Prior rounds measured ~33% occupancy with 256-thread blocks.
// ---------------------------------------------------------------------------
__global__ __launch_bounds__(512, 4) void gemm_hist_kernel(const float* __restrict__ x,
                                                           const unsigned short* __restrict__ wbf,
                                                           unsigned short* __restrict__ pre,
                                                           const int* __restrict__ rows,
                                                           int* __restrict__ deg) {
    __shared__ __align__(16) unsigned short wt[IN_DIM * OUT_DIM];   // 32 KB exactly

    const int tid = threadIdx.x;
    const int wave = tid >> 6;          // 0..7
    const int lane = tid & 63;
    const int ln16 = lane & 15;
    const int quad = lane >> 4;

    // W staging: 512 threads x 16B x 4 iterations = 32 KB.
    #pragma unroll
    for (int i = 0; i < 4; ++i)
        *(bf16x8*)&wt[i * 4096 + tid * 8] = *(const bf16x8*)(wbf + i * 4096 + tid * 8);

    const int R0 = blockIdx.x * 128;
    const int arow = R0 + wave * 16 + ln16;
    const float* xrow = x + (size_t)(arow < N_NODES ? arow : N_NODES - 1) * IN_DIM + quad * 8;

    __syncthreads();

    f32x4 acc[4] = {};

    #pragma unroll
    for (int kt = 0; kt < 8; ++kt) {
        f32x4 xa = *(const f32x4*)(xrow + kt * 32);
        f32x4 xb = *(const f32x4*)(xrow + kt * 32 + 4);
        bf16x8 a;
        a[0] = (short)f32_to_bf16(xa.x); a[1] = (short)f32_to_bf16(xa.y);
        a[2] = (short)f32_to_bf16(xa.z); a[3] = (short)f32_to_bf16(xa.w);
        a[4] = (short)f32_to_bf16(xb.x); a[5] = (short)f32_to_bf16(xb.y);
        a[6] = (short)f32_to_bf16(xb.z); a[7] = (short)f32_to_bf16(xb.w);
        #pragma unroll
        for (int t = 0; t < 4; ++t) {
            bf16x8 b = *(const bf16x8*)&wt[((kt * 4 + t) * 64 + lane) * 8];
            acc[t] = __builtin_amdgcn_mfma_f32_16x16x32_bf16(a, b, acc[t], 0, 0, 0);
        }
    }

    const int rbase = R0 + wave * 16 + quad * 4;
    #pragma unroll
    for (int t = 0; t < 4; ++t) {
        #pragma unroll
        for (int r = 0; r < 4; ++r) {
            const int rr = rbase + r;
            if (rr < N_NODES)
                pre[(size_t)rr * OUT_DIM + t * 16 + ln16] = f32_to_bf16(acc[t][r]);
        }
    }

    // ---- hist tail: grid-stride over edges, fire-and-forget atomics ----
    for (int e = blockIdx.x * 512 + tid; e < N_EDGES; e += GB2 * 512) {
        atomicAdd(&deg[rows[e]], 1);
    }
}

__global__ __launch_bounds__(256) void scan1_kernel(const int* __restrict__ deg,
                                                    int* __restrict__ off,
                                                    int* __restrict__ bsum) {
    __shared__ int s[256];
    const int t = threadIdx.x;
    const int base = blockIdx.x * 1024 + t * 4;
    int d[4];
    #pragma unroll
    for (int q = 0; q < 4; ++q) {
        const int i = base + q;
        d[q] = i < N_NODES ? deg[i] : 0;
    }
    const int tsum = d[0] + d[1] + d[2] + d[3];
    s[t] = tsum;
    __syncthreads();
    #pragma unroll
    for (int o = 1; o < 256; o <<= 1) {
        const int add = t >= o ? s[t - o] : 0;
        __syncthreads();
        s[t] += add;
        __syncthreads();
    }
    int run = t > 0 ? s[t - 1] : 0;
    #pragma unroll
    for (int q = 0; q < 4; ++q) {
        const int i = base + q;
        if (i < N_NODES) off[i] = run;
        run += d[q];
    }
    if (t == 255) bsum[blockIdx.x] = run;
}

__global__ __launch_bounds__(128) void scan2_kernel(const int* __restrict__ bsum,
                                                    int* __restrict__ boff,
                                                    int* __restrict__ off) {
    __shared__ int s[128];
    const int t = threadIdx.x;
    const int v = t < NB1 ? bsum[t] : 0;
    s[t] = v;
    __syncthreads();
    #pragma unroll
    for (int o = 1; o < 128; o <<= 1) {
        const int add = t >= o ? s[t - o] : 0;
        __syncthreads();
        s[t] += add;
        __syncthreads();
    }
    if (t < NB1) boff[t] = t > 0 ? s[t - 1] : 0;
    if (t == 127) off[N_NODES] = s[127];
}

__global__ __launch_bounds__(256) void scan3_kernel(int* __restrict__ off,
                                                    const int* __restrict__ boff,
                                                    int* __restrict__ cursor) {
    const int i = blockIdx.x * 256 + threadIdx.x;
    if (i < N_NODES) {
        const int v = off[i] + boff[i >> 10];
        off[i] = v;
        cursor[i] = v;
    }
}

// ---------------------------------------------------------------------------
// Reorder, XCD-partitioned (round-7 note: fixes cross-XCD partial-line write
// amplification). 5000 blocks: 625 chunks x 8 partitions; chunk = 2048 edges.
// ---------------------------------------------------------------------------
__global__ __launch_bounds__(256) void reorder_kernel(const int* __restrict__ rows,
                                                      const int* __restrict__ cols,
                                                      const float* __restrict__ vals,
                                                      int* __restrict__ cursor,
                                                      unsigned long long* __restrict__ epack) {
    const int part = blockIdx.x & 7;
    const int lo = part * PART_SZ;
    const int hi = lo + PART_SZ;            // partition 7: 87500..100000
    const int base = (blockIdx.x >> 3) * 2048 + threadIdx.x;
    #pragma unroll
    for (int k = 0; k < 8; ++k) {
        const int e = base + k * 256;
        const int r = rows[e];
        if (r >= lo && r < hi) {
            const int c = cols[e];
            const float v = vals[e];
            const int slot = atomicAdd(&cursor[r], 1);
            epack[slot] = ((unsigned long long)__float_as_uint(v) << 32) | (unsigned int)c;
        }
    }
}

// ---------------------------------------------------------------------------
// Gather: one wave per node, lane = dim, 4-deep ILP. pre is bf16 (128B/edge).
// Fused bias + ReLU. Zero atomics.
// ---------------------------------------------------------------------------
__global__ __launch_bounds__(256) void gather_kernel(const int* __restrict__ off,
                                                     const unsigned long long* __restrict__ epack,
                                                     const unsigned short* __restrict__ pre,
                                                     const float* __restrict__ bias,
                                                     float* __restrict__ out) {
    const int v = blockIdx.x * 4 + (threadIdx.x >> 6);
    const int j = threadIdx.x & 63;
    if (v >= N_NODES) return;
    const int s = off[v];
    const int e = off[v + 1];
    float acc = 0.0f;
    int i = s;
    for (; i + 4 <= e; i += 4) {
        unsigned long long ee[4];
        float p[4];
        #pragma unroll
        for (int q = 0; q < 4; ++q) ee[q] = epack[i + q];
        #pragma unroll
        for (int q = 0; q < 4; ++q)
            p[q] = bf16_to_f32(pre[(size_t)(unsigned int)(ee[q] & 0xffffffffu) * OUT_DIM + j]);
        #pragma unroll
        for (int q = 0; q < 4; ++q)
            acc = fmaf(p[q], __uint_as_float((unsigned int)(ee[q] >> 32)), acc);
    }
    for (; i < e; ++i) {
        const unsigned long long e0 = epack[i];
        acc = fmaf(bf16_to_f32(pre[(size_t)(unsigned int)(e0 & 0xffffffffu) * OUT_DIM + j]),
                   __uint_as_float((unsigned int)(e0 >> 32)), acc);
    }
    const float r = acc + bias[j];
    out[(size_t)v * OUT_DIM + j] = r > 0.0f ? r : 0.0f;
}

extern "C" void kernel_launch(void* const* d_in, const int* in_sizes, int n_in,
                              void* d_out, int out_size, void* d_ws, size_t ws_size,
                              hipStream_t stream) {
    const float* x    = (const float*)d_in[0];
    const int* rows   = (const int*)d_in[1];
    const int* cols   = (const int*)d_in[2];
    const float* vals = (const float*)d_in[3];
    const float* w    = (const float*)d_in[4];
    const float* bias = (const float*)d_in[5];
    float* out        = (float*)d_out;

    unsigned short* pre = (unsigned short*)d_ws;               // 12.8 MB bf16
    int* deg    = (int*)(pre + (size_t)N_NODES * OUT_DIM);
    int* off    = deg + N_NODES;                               // N_NODES+1 (+pad)
    int* cursor = off + N_NODES + 4;                           // 16B-aligned
    int* bsum   = cursor + N_NODES;                            // 128
    int* boff   = bsum + 128;                                  // 128
    unsigned long long* epack = (unsigned long long*)(boff + 128); // 10.24 MB, 8B-aligned

    // wbf (32 KB) overlays cursor: written by wpack, read by gemm; cursor is
    // only written later (scan3) -- no overlap in lifetime.
    unsigned short* wbf = (unsigned short*)cursor;

    wpack_zero_kernel<<<NB1, 256, 0, stream>>>(w, wbf, deg);

    gemm_hist_kernel<<<GB2, 512, 0, stream>>>(x, wbf, pre, rows, deg);

    scan1_kernel<<<NB1, 256, 0, stream>>>(deg, off, bsum);
    scan2_kernel<<<1, 128, 0, stream>>>(bsum, boff, off);
    scan3_kernel<<<(N_NODES + 255) / 256, 256, 0, stream>>>(off, boff, cursor);

    reorder_kernel<<<5000, 256, 0, stream>>>(rows, cols, vals, cursor, epack);

    gather_kernel<<<(N_NODES + 3) / 4, 256, 0, stream>>>(off, epack, pre, bias, out);
}

// Round 8
// 322.672 us; speedup vs baseline: 1.0960x; 1.0960x over previous
//
#include <hip/hip_runtime.h>
#include <hip/hip_bf16.h>
#include <stdint.h>

#define N_NODES 100000
#define N_EDGES 1280000
#define IN_DIM  256
#define OUT_DIM 64
#define NB1     98          // ceil(100000/1024) scan blocks
#define GEMM_BLOCKS ((N_NODES + 63) / 64)   // 1563
#define PART_SZ 12500       // nodes per XCD partition (100000/8)

// zero-global-atomic histogram: 4 bin-slices x 50 edge-chunks
#define HSL   4             // slices of 25000 bins (50 KB packed-u16 LDS)
#define HSB   25000         // bins per slice
#define HCH   50            // edge chunks
#define HEPC  (N_EDGES / HCH)   // 25600 edges per chunk (< 65536: u16-safe)

typedef __attribute__((ext_vector_type(8))) short bf16x8;
typedef __attribute__((ext_vector_type(4))) float f32x4;
typedef __attribute__((ext_vector_type(4))) unsigned short u16x4;

__device__ __forceinline__ unsigned short f32_to_bf16(float f) {
    union { float f; unsigned int u; } c; c.f = f;
    unsigned int u = c.u;
    u += 0x7fffu + ((u >> 16) & 1u);   // RNE
    return (unsigned short)(u >> 16);
}
__device__ __forceinline__ float bf16_to_f32(unsigned short h) {
    union { unsigned int u; float f; } c; c.u = ((unsigned int)h) << 16; return c.f;
}

// ---------------------------------------------------------------------------
// K0: one-time W pack (f32 -> bf16, B-fragment order), 16 blocks.
// ---------------------------------------------------------------------------
__global__ __launch_bounds__(256) void wpack_kernel(const float* __restrict__ w,
                                                    unsigned short* __restrict__ wbf) {
    const int i0 = blockIdx.x * 1024;
    for (int i = i0 + threadIdx.x; i < i0 + 1024; i += 256) {
        const int k = i >> 6, n = i & 63;
        const int kt = k >> 5, q = (k >> 3) & 3, j = k & 7;
        const int t = n >> 4, l = n & 15;
        wbf[((kt * 4 + t) * 64 + q * 16 + l) * 8 + j] = f32_to_bf16(w[i]);
    }
}

// ---------------------------------------------------------------------------
// K_hist: ZERO global atomics. Round-15 diagnosis: WRITE_SIZE 52.4 MB vs
// 12.8 MB of pre writes => the 1.28M deg atomicAdds cost ~80 MB of
// serialized LLC RMW (device-scope atomics bypass the non-coherent per-XCD
// L2) — ~45 of gemm_hist's ~70us. Four GEMM-side scheduling rounds bounced
// off this floor. Here: block (slice s, chunk c) counts its 25600-edge chunk
// into 25000 bins held as PACKED u16 PAIRS in u32 LDS (50 KB): bin d ->
// atomicAdd(lh[d>>1], 1<<((d&1)*16)); max count 25600 < 65536 so no carry
// into the neighbor half. Stripe written non-atomically as u16 partials into
// the dead epack region; scan1 sums the 50 partials per node.
// ---------------------------------------------------------------------------
__global__ __launch_bounds__(256) void hist_kernel(const int* __restrict__ rows,
                                                   unsigned short* __restrict__ partial) {
    __shared__ unsigned int lh[HSB / 2];          // 50 KB
    const int s = blockIdx.x & 3;                 // slice
    const int c = blockIdx.x >> 2;                // chunk
    const int lo = s * HSB;
    for (int i = threadIdx.x; i < HSB / 2; i += 256) lh[i] = 0u;
    __syncthreads();
    const int4* rp = (const int4*)(rows + c * HEPC);
    for (int i = threadIdx.x; i < HEPC / 4; i += 256) {   // 25 iterations
        const int4 r4 = rp[i];
        const unsigned d0 = (unsigned)(r4.x - lo);
        const unsigned d1 = (unsigned)(r4.y - lo);
        const unsigned d2 = (unsigned)(r4.z - lo);
        const unsigned d3 = (unsigned)(r4.w - lo);
        if (d0 < HSB) atomicAdd(&lh[d0 >> 1], 1u << ((d0 & 1) * 16));
        if (d1 < HSB) atomicAdd(&lh[d1 >> 1], 1u << ((d1 & 1) * 16));
        if (d2 < HSB) atomicAdd(&lh[d2 >> 1], 1u << ((d2 & 1) * 16));
        if (d3 < HSB) atomicAdd(&lh[d3 >> 1], 1u << ((d3 & 1) * 16));
    }
    __syncthreads();
    // packed u32 word i = bins (2i, 2i+1) lo/hi -> little-endian u16 store.
    unsigned int* dst = (unsigned int*)(partial + (size_t)c * N_NODES + lo);
    for (int i = threadIdx.x; i < HSB / 2; i += 256) dst[i] = lh[i];
}

// ---------------------------------------------------------------------------
// K1: GEMM only (pre[N][64] bf16 = bf16(X)@bf16(W), MFMA 16x16x32).
// Round-2's proven structure (best measured) with the atomic hist tail
// REMOVED — it was ~45us of the fused kernel's ~70us.
// ---------------------------------------------------------------------------
__global__ __launch_bounds__(256, 4) void gemm_kernel(const float* __restrict__ x,
                                                      const unsigned short* __restrict__ wbf,
                                                      unsigned short* __restrict__ pre) {
    __shared__ __align__(16) unsigned short wt[IN_DIM * OUT_DIM];   // 32 KB

    const int tid = threadIdx.x;
    const int wave = tid >> 6;
    const int lane = tid & 63;
    const int ln16 = lane & 15;
    const int quad = lane >> 4;

    const int R0 = blockIdx.x * 64;
    const int arow = R0 + wave * 16 + ln16;
    const float* xrow = x + (size_t)(arow < N_NODES ? arow : N_NODES - 1) * IN_DIM + quad * 8;

    f32x4 xa[8], xb[8];
    #pragma unroll
    for (int kt = 0; kt < 8; ++kt) {
        xa[kt] = *(const f32x4*)(xrow + kt * 32);
        xb[kt] = *(const f32x4*)(xrow + kt * 32 + 4);
    }

    #pragma unroll
    for (int i = 0; i < 8; ++i)
        *(bf16x8*)&wt[i * 2048 + tid * 8] = *(const bf16x8*)(wbf + i * 2048 + tid * 8);

    __syncthreads();

    f32x4 acc[4] = {};

    #pragma unroll
    for (int kt = 0; kt < 8; ++kt) {
        bf16x8 a;
        a[0] = (short)f32_to_bf16(xa[kt].x); a[1] = (short)f32_to_bf16(xa[kt].y);
        a[2] = (short)f32_to_bf16(xa[kt].z); a[3] = (short)f32_to_bf16(xa[kt].w);
        a[4] = (short)f32_to_bf16(xb[kt].x); a[5] = (short)f32_to_bf16(xb[kt].y);
        a[6] = (short)f32_to_bf16(xb[kt].z); a[7] = (short)f32_to_bf16(xb[kt].w);
        #pragma unroll
        for (int t = 0; t < 4; ++t) {
            bf16x8 b = *(const bf16x8*)&wt[((kt * 4 + t) * 64 + lane) * 8];
            acc[t] = __builtin_amdgcn_mfma_f32_16x16x32_bf16(a, b, acc[t], 0, 0, 0);
        }
    }

    const int rbase = R0 + wave * 16 + quad * 4;
    #pragma unroll
    for (int t = 0; t < 4; ++t) {
        #pragma unroll
        for (int r = 0; r < 4; ++r) {
            const int rr = rbase + r;
            if (rr < N_NODES)
                pre[(size_t)rr * OUT_DIM + t * 16 + ln16] = f32_to_bf16(acc[t][r]);
        }
    }
}

// ---------------------------------------------------------------------------
// scan1: per-node degree = sum of 50 u16 chunk-partials, then prefix scan.
// ---------------------------------------------------------------------------
__global__ __launch_bounds__(256) void scan1_kernel(const unsigned short* __restrict__ partial,
                                                    int* __restrict__ off,
                                                    int* __restrict__ bsum) {
    __shared__ int s[256];
    const int t = threadIdx.x;
    const int base = blockIdx.x * 1024 + t * 4;
    int d[4] = {0, 0, 0, 0};
    for (int c = 0; c < HCH; ++c) {
        const u16x4 v = *(const u16x4*)(partial + (size_t)c * N_NODES + base);
        d[0] += v[0]; d[1] += v[1]; d[2] += v[2]; d[3] += v[3];
    }
    #pragma unroll
    for (int q = 0; q < 4; ++q)
        if (base + q >= N_NODES) d[q] = 0;
    const int tsum = d[0] + d[1] + d[2] + d[3];
    s[t] = tsum;
    __syncthreads();
    #pragma unroll
    for (int o = 1; o < 256; o <<= 1) {
        const int add = t >= o ? s[t - o] : 0;
        __syncthreads();
        s[t] += add;
        __syncthreads();
    }
    int run = t > 0 ? s[t - 1] : 0;
    #pragma unroll
    for (int q = 0; q < 4; ++q) {
        const int i = base + q;
        if (i < N_NODES) off[i] = run;
        run += d[q];
    }
    if (t == 255) bsum[blockIdx.x] = run;
}

__global__ __launch_bounds__(128) void scan2_kernel(const int* __restrict__ bsum,
                                                    int* __restrict__ boff,
                                                    int* __restrict__ off) {
    __shared__ int s[128];
    const int t = threadIdx.x;
    const int v = t < NB1 ? bsum[t] : 0;
    s[t] = v;
    __syncthreads();
    #pragma unroll
    for (int o = 1; o < 128; o <<= 1) {
        const int add = t >= o ? s[t - o] : 0;
        __syncthreads();
        s[t] += add;
        __syncthreads();
    }
    if (t < NB1) boff[t] = t > 0 ? s[t - 1] : 0;
    if (t == 127) off[N_NODES] = s[127];
}

__global__ __launch_bounds__(256) void scan3_kernel(int* __restrict__ off,
                                                    const int* __restrict__ boff,
                                                    int* __restrict__ cursor) {
    const int i = blockIdx.x * 256 + threadIdx.x;
    if (i < N_NODES) {
        const int v = off[i] + boff[i >> 10];
        off[i] = v;
        cursor[i] = v;
    }
}

// ---------------------------------------------------------------------------
// Reorder, XCD-partitioned (fixes cross-XCD partial-line write
// amplification). 5000 blocks: 625 chunks x 8 partitions; chunk = 2048 edges.
// ---------------------------------------------------------------------------
__global__ __launch_bounds__(256) void reorder_kernel(const int* __restrict__ rows,
                                                      const int* __restrict__ cols,
                                                      const float* __restrict__ vals,
                                                      int* __restrict__ cursor,
                                                      unsigned long long* __restrict__ epack) {
    const int part = blockIdx.x & 7;
    const int lo = part * PART_SZ;
    const int hi = lo + PART_SZ;            // partition 7: 87500..100000
    const int base = (blockIdx.x >> 3) * 2048 + threadIdx.x;
    #pragma unroll
    for (int k = 0; k < 8; ++k) {
        const int e = base + k * 256;
        const int r = rows[e];
        if (r >= lo && r < hi) {
            const int c = cols[e];
            const float v = vals[e];
            const int slot = atomicAdd(&cursor[r], 1);
            epack[slot] = ((unsigned long long)__float_as_uint(v) << 32) | (unsigned int)c;
        }
    }
}

// ---------------------------------------------------------------------------
// Gather: one wave per node, lane = dim, 4-deep ILP. pre is bf16 (128B/edge).
// Fused bias + ReLU. Zero atomics.
// ---------------------------------------------------------------------------
__global__ __launch_bounds__(256) void gather_kernel(const int* __restrict__ off,
                                                     const unsigned long long* __restrict__ epack,
                                                     const unsigned short* __restrict__ pre,
                                                     const float* __restrict__ bias,
                                                     float* __restrict__ out) {
    const int v = blockIdx.x * 4 + (threadIdx.x >> 6);
    const int j = threadIdx.x & 63;
    if (v >= N_NODES) return;
    const int s = off[v];
    const int e = off[v + 1];
    float acc = 0.0f;
    int i = s;
    for (; i + 4 <= e; i += 4) {
        unsigned long long ee[4];
        float p[4];
        #pragma unroll
        for (int q = 0; q < 4; ++q) ee[q] = epack[i + q];
        #pragma unroll
        for (int q = 0; q < 4; ++q)
            p[q] = bf16_to_f32(pre[(size_t)(unsigned int)(ee[q] & 0xffffffffu) * OUT_DIM + j]);
        #pragma unroll
        for (int q = 0; q < 4; ++q)
            acc = fmaf(p[q], __uint_as_float((unsigned int)(ee[q] >> 32)), acc);
    }
    for (; i < e; ++i) {
        const unsigned long long e0 = epack[i];
        acc = fmaf(bf16_to_f32(pre[(size_t)(unsigned int)(e0 & 0xffffffffu) * OUT_DIM + j]),
                   __uint_as_float((unsigned int)(e0 >> 32)), acc);
    }
    const float r = acc + bias[j];
    out[(size_t)v * OUT_DIM + j] = r > 0.0f ? r : 0.0f;
}

extern "C" void kernel_launch(void* const* d_in, const int* in_sizes, int n_in,
                              void* d_out, int out_size, void* d_ws, size_t ws_size,
                              hipStream_t stream) {
    const float* x    = (const float*)d_in[0];
    const int* rows   = (const int*)d_in[1];
    const int* cols   = (const int*)d_in[2];
    const float* vals = (const float*)d_in[3];
    const float* w    = (const float*)d_in[4];
    const float* bias = (const float*)d_in[5];
    float* out        = (float*)d_out;

    unsigned short* pre = (unsigned short*)d_ws;               // 12.8 MB bf16
    int* off    = (int*)(pre + (size_t)N_NODES * OUT_DIM);     // N_NODES+1 (+pad)
    int* cursor = off + N_NODES + 4;                           // 16B-aligned
    int* bsum   = cursor + N_NODES;                            // 128
    int* boff   = bsum + 128;                                  // 128
    unsigned long long* epack = (unsigned long long*)(boff + 128); // 10.24 MB, 8B-aligned

    // partial (10.0 MB u16, 50 chunks x 100000 nodes) overlays epack: written
    // by hist, read by scan1; epack is only written later (reorder).
    unsigned short* partial = (unsigned short*)epack;
    // wbf (32 KB) overlays cursor: written by wpack, read by gemm; cursor is
    // only written later (scan3).
    unsigned short* wbf = (unsigned short*)cursor;

    wpack_kernel<<<16, 256, 0, stream>>>(w, wbf);

    hist_kernel<<<HSL * HCH, 256, 0, stream>>>(rows, partial);

    gemm_kernel<<<GEMM_BLOCKS, 256, 0, stream>>>(x, wbf, pre);

    scan1_kernel<<<NB1, 256, 0, stream>>>(partial, off, bsum);
    scan2_kernel<<<1, 128, 0, stream>>>(bsum, boff, off);
    scan3_kernel<<<(N_NODES + 255) / 256, 256, 0, stream>>>(off, boff, cursor);

    reorder_kernel<<<5000, 256, 0, stream>>>(rows, cols, vals, cursor, epack);

    gather_kernel<<<(N_NODES + 3) / 4, 256, 0, stream>>>(off, epack, pre, bias, out);
}